// Round 10
// baseline (190.194 us; speedup 1.0000x reference)
//
#include <hip/hip_runtime.h>
#include <hip/hip_bf16.h>
#include <stdint.h>

#define SEQ   2048
#define NBH   64      // B*H
#define DH    64
#define CH    1024
#define MTOT  8192    // B*SEQ
// 1/sqrt(64) * log2(e): QK^T is computed in log2 domain, softmax uses v_exp_f32 (2^x)
#define QSCALE 0.1803368801111204f

typedef __bf16 bf16_t;
typedef bf16_t bf16x8 __attribute__((ext_vector_type(8)));
typedef float  f32x4  __attribute__((ext_vector_type(4)));
typedef float  f32x16 __attribute__((ext_vector_type(16)));

__device__ __forceinline__ bf16_t to_bf16(float f) {
  uint32_t u = __builtin_bit_cast(uint32_t, f);
  uint16_t r = (uint16_t)((u + 0x7fffu + ((u >> 16) & 1u)) >> 16);
  return __builtin_bit_cast(bf16_t, r);
}

__device__ __forceinline__ void gload_lds16(const void* g, void* l) {
  __builtin_amdgcn_global_load_lds(
      (const __attribute__((address_space(1))) uint32_t*)g,
      (__attribute__((address_space(3))) uint32_t*)l, 16, 0, 0);
}

__device__ __forceinline__ f32x4 mfma_bf16(bf16x8 a, bf16x8 b, f32x4 c) {
  return __builtin_amdgcn_mfma_f32_16x16x32_bf16(a, b, c, 0, 0, 0);
}
__device__ __forceinline__ f32x16 mfma32_bf16(bf16x8 a, bf16x8 b, f32x16 c) {
  return __builtin_amdgcn_mfma_f32_32x32x16_bf16(a, b, c, 0, 0, 0);
}

__device__ __forceinline__ float exp2_fast(float x) {
#if __has_builtin(__builtin_amdgcn_exp2f)
  return __builtin_amdgcn_exp2f(x);
#else
  float r;
  asm("v_exp_f32 %0, %1\ns_nop 0" : "=v"(r) : "v"(x));
  return r;
#endif
}

// dst.lo16 = bf16(lo), dst.hi16 = bf16(hi), RNE
__device__ __forceinline__ uint32_t cvt_pk_bf16(float lo, float hi) {
  uint32_t r;
  asm("v_cvt_pk_bf16_f32 %0, %1, %2" : "=v"(r) : "v"(lo), "v"(hi));
  return r;
}

// After: a = {a.lanes0-31, b.lanes0-31}, b = {a.lanes32-63, b.lanes32-63}
__device__ __forceinline__ void permlane32_swap(uint32_t& a, uint32_t& b) {
  asm("s_nop 1\n\tv_permlane32_swap_b32 %0, %1\n\ts_nop 1" : "+v"(a), "+v"(b));
}

// ---------------- merged prep: x->bf16 cvt + both weight transposes ----------
// blocks [0,2048): cvt x (grid-stride); [2048,2816): w_qkv^T; [2816,3072): w_out^T
__global__ __launch_bounds__(256) void prep(
    const float* __restrict__ x, bf16_t* __restrict__ xb,
    const float* __restrict__ w_qkv, bf16_t* __restrict__ wqkvT,
    const float* __restrict__ w_out, bf16_t* __restrict__ woT) {
  __shared__ float t[64 * 65];
  const int tid = threadIdx.x;
  const int blk = blockIdx.x;
  if (blk < 2048) {
    int i = (blk * 256 + tid) * 4;
    const int stride = 2048 * 256 * 4;
    for (; i < MTOT * CH; i += stride) {
      const float4 f = *reinterpret_cast<const float4*>(x + i);
      bf16_t tmp[4] = {to_bf16(f.x), to_bf16(f.y), to_bf16(f.z), to_bf16(f.w)};
      *reinterpret_cast<uint2*>(xb + i) = *reinterpret_cast<uint2*>(tmp);
    }
    return;
  }
  const float* W; bf16_t* WT; int Nd, nx, bi;
  if (blk < 2048 + 768) { bi = blk - 2048; W = w_qkv; WT = wqkvT; Nd = 3 * CH; nx = 48; }
  else                  { bi = blk - 2816; W = w_out; WT = woT;   Nd = CH;     nx = 16; }
  const int n0 = (bi % nx) * 64, k0 = (bi / nx) * 64;
#pragma unroll
  for (int rr = 0; rr < 16; ++rr) {
    const int idx = rr * 256 + tid;
    const int r = idx >> 6, c = idx & 63;
    t[r * 65 + c] = W[(size_t)(k0 + r) * Nd + n0 + c];
  }
  __syncthreads();
#pragma unroll
  for (int rr = 0; rr < 16; ++rr) {
    const int idx = rr * 256 + tid;
    const int nr = idx >> 6, kc = idx & 63;
    WT[(size_t)(n0 + nr) * CH + k0 + kc] = to_bf16(t[kc * 65 + nr]);
  }
}

// ------- GEMM 256x128 tile, BK=64, 8 waves, dbuf LDS, counted vmcnt ---------
// A [M][1024] x BT [N][1024].  EPI 0: scatter Q (log2-scaled), K, V^T.
// EPI 1: +bias, fp32 out.  1D grid (nwg % 8 == 0), nx = N/128.
// Per K-tile: vmcnt(6)+barrier -> 20 ds_read_b128 + 32 MFMA -> barrier ->
// stage(kt+2).  Loads stay >= 2 K-tiles in flight; never drained mid-loop.
template <int EPI>
__global__ __launch_bounds__(512, 1) void gemm_bt(
    const bf16_t* __restrict__ A, const bf16_t* __restrict__ BT, int nx,
    bf16_t* __restrict__ qb, bf16_t* __restrict__ kb, bf16_t* __restrict__ vb,
    const float* __restrict__ bias, float* __restrict__ out) {
  __shared__ __attribute__((aligned(16))) bf16_t lA[2][256 * 64];   // 64 KB
  __shared__ __attribute__((aligned(16))) bf16_t lB[2][128 * 64];   // 32 KB
  const int tid = threadIdx.x;       // 0..511
  const int lane = tid & 63;
  const int wv = tid >> 6;           // 0..7
  const int wr = wv >> 2, wc = wv & 3;
  const int l15 = lane & 15, l16 = lane >> 4;

  // XCD-aware bijective swizzle (nwg % 8 == 0)
  const int nwg = gridDim.x;
  int bid = blockIdx.x;
  bid = (bid & 7) * (nwg >> 3) + (bid >> 3);
  const int m0 = (bid / nx) * 256, n0 = (bid % nx) * 128;

  f32x4 acc[8][2] = {};

  const int srow = tid >> 3;         // 0..63
  const int sch = tid & 7;

  auto stage = [&](int buf, int kt) {
#pragma unroll
    for (int c = 0; c < 4; ++c) {
      const int row = c * 64 + srow;
      const int cs = sch ^ (row & 7);
      gload_lds16(A + (size_t)(m0 + row) * CH + kt + cs * 8,
                  reinterpret_cast<char*>(&lA[buf][0]) + c * 8192 + tid * 16);
    }
#pragma unroll
    for (int c = 0; c < 2; ++c) {
      const int row = c * 64 + srow;
      const int cs = sch ^ (row & 7);
      gload_lds16(BT + (size_t)(n0 + row) * CH + kt + cs * 8,
                  reinterpret_cast<char*>(&lB[buf][0]) + c * 8192 + tid * 16);
    }
  };

  stage(0, 0);
  stage(1, 64);

  for (int kt = 0; kt < 16; ++kt) {
    if (kt < 15)
      asm volatile("s_waitcnt vmcnt(6)\n\ts_barrier" ::: "memory");
    else
      asm volatile("s_waitcnt vmcnt(0)\n\ts_barrier" ::: "memory");
    const char* lap = reinterpret_cast<const char*>(&lA[kt & 1][0]);
    const char* lbp = reinterpret_cast<const char*>(&lB[kt & 1][0]);

    __builtin_amdgcn_s_setprio(1);
    bf16x8 bfr[2][2];
#pragma unroll
    for (int j = 0; j < 2; ++j) {
      const int br = wc * 32 + j * 16 + l15;
#pragma unroll
      for (int ks = 0; ks < 2; ++ks) {
        const int ch = (ks * 4 + l16) ^ (br & 7);
        bfr[j][ks] = *reinterpret_cast<const bf16x8*>(lbp + br * 128 + ch * 16);
      }
    }
#pragma unroll
    for (int i = 0; i < 8; ++i) {
      const int ar = wr * 128 + i * 16 + l15;
      const int ch0 = l16 ^ (ar & 7);
      const bf16x8 af0 = *reinterpret_cast<const bf16x8*>(lap + ar * 128 + ch0 * 16);
      const int ch1 = (4 + l16) ^ (ar & 7);
      const bf16x8 af1 = *reinterpret_cast<const bf16x8*>(lap + ar * 128 + ch1 * 16);
#pragma unroll
      for (int j = 0; j < 2; ++j) {
        acc[i][j] = mfma_bf16(af0, bfr[j][0], acc[i][j]);
        acc[i][j] = mfma_bf16(af1, bfr[j][1], acc[i][j]);
      }
    }
    __builtin_amdgcn_s_setprio(0);

    asm volatile("s_barrier" ::: "memory");   // all waves done reading buf[kt&1]
    if (kt + 2 < 16) stage(kt & 1, (kt + 2) * 64);
  }

  if (EPI == 0) {
    const int f0 = n0 + wc * 32;
    const int three = n0 >> 10;   // block-uniform (128-tile never crosses 1024)
    if (three < 2) {
#pragma unroll
      for (int i = 0; i < 8; ++i) {
#pragma unroll
        for (int j = 0; j < 2; ++j) {
#pragma unroll
          for (int r = 0; r < 4; ++r) {
            const int m = m0 + wr * 128 + i * 16 + l16 * 4 + r;
            const int f = f0 + j * 16 + l15;
            const int h = (f >> 6) & 15, d = f & 63;
            const int bh = (m >> 11) * 16 + h;
            const int n = m & 2047;
            const float val = acc[i][j][r];
            if (three == 0)
              qb[((size_t)bh * SEQ + n) * DH + d] = to_bf16(val * QSCALE);
            else
              kb[((size_t)bh * SEQ + n) * DH + d] = to_bf16(val);
          }
        }
      }
    } else {
      // V^T: 4 consecutive n (r=0..3) at fixed d -> one packed 8B store
#pragma unroll
      for (int i = 0; i < 8; ++i) {
#pragma unroll
        for (int j = 0; j < 2; ++j) {
          const int m = m0 + wr * 128 + i * 16 + l16 * 4;   // r=0
          const int f = f0 + j * 16 + l15;
          const int h = (f >> 6) & 15, d = f & 63;
          const int bh = (m >> 11) * 16 + h;
          const int n = m & 2047;
          const uint2 pk = make_uint2(cvt_pk_bf16(acc[i][j][0], acc[i][j][1]),
                                      cvt_pk_bf16(acc[i][j][2], acc[i][j][3]));
          *reinterpret_cast<uint2*>(&vb[((size_t)bh * DH + d) * SEQ + n]) = pk;
        }
      }
    }
  } else {
#pragma unroll
    for (int j = 0; j < 2; ++j) {
      const int cc = n0 + wc * 32 + j * 16 + l15;
      const float bb = bias[cc];
#pragma unroll
      for (int i = 0; i < 8; ++i) {
#pragma unroll
        for (int r = 0; r < 4; ++r) {
          const int m = m0 + wr * 128 + i * 16 + l16 * 4 + r;
          out[(size_t)m * CH + cc] = acc[i][j][r] + bb;
        }
      }
    }
  }
}

// ---------------- flash attention (32x32 MFMA, in-register P via permlane) ----
// grid = 1024 (XCD-swizzled), block = 256 (4 waves x 32 q-rows)
// Proven-best structure (81 us): 2-buffer K/V, __syncthreads per tile.
__global__ __launch_bounds__(256, 4) void attn_fwd(
    const bf16_t* __restrict__ Q, const bf16_t* __restrict__ K,
    const bf16_t* __restrict__ V, bf16_t* __restrict__ O) {
  __shared__ __attribute__((aligned(16))) bf16_t lK[2][64 * 64];
  __shared__ __attribute__((aligned(16))) bf16_t lV[2][64 * 64];   // V^T tile [d][kt]
  const int tid = threadIdx.x;
  const int lane = tid & 63;
  const int wv = tid >> 6;
  const int l31 = lane & 31, hi = lane >> 5;

  // XCD swizzle: each XCD owns 8 consecutive bh (K/V footprint 4MB = one L2)
  const int lin = blockIdx.x;
  const int bh = (lin & 7) * 8 + ((lin >> 3) & 7);
  const int qb = lin >> 6;
  const int q0w = qb * 128 + wv * 32;

  const bf16_t* Qb = Q + (size_t)bh * SEQ * DH;
  const bf16_t* Kb = K + (size_t)bh * SEQ * DH;
  const bf16_t* Vb = V + (size_t)bh * DH * SEQ;

  // Q fragments (B-operand of 32x32x16): lane holds Q[q0w + l31][ks*16 + hi*8 + j]
  bf16x8 qf[4];
#pragma unroll
  for (int ks = 0; ks < 4; ++ks)
    qf[ks] = *reinterpret_cast<const bf16x8*>(
        Qb + (size_t)(q0w + l31) * DH + ks * 16 + hi * 8);

  f32x16 o0 = {}, o1 = {};   // O[q=crow(r,hi)][d = db*32 + l31]
  float rs0 = 0.f, rs1 = 0.f, rs2 = 0.f, rs3 = 0.f;  // partial denoms (q = l31)

  const int srow = tid >> 3;
  const int sch = tid & 7;

  auto stage = [&](int buf, int kt0) {
#pragma unroll
    for (int c = 0; c < 2; ++c) {
      const int row = c * 32 + srow;
      const int cs = sch ^ (row & 7);
      gload_lds16(Kb + (size_t)(kt0 + row) * DH + cs * 8,
                  reinterpret_cast<char*>(&lK[buf][0]) + c * 4096 + tid * 16);
      gload_lds16(Vb + (size_t)row * SEQ + kt0 + cs * 8,
                  reinterpret_cast<char*>(&lV[buf][0]) + c * 4096 + tid * 16);
    }
  };

  stage(0, 0);
  __syncthreads();
  int cur = 0;

  for (int t = 0; t < SEQ / 64; ++t) {
    if (t + 1 < SEQ / 64) stage(cur ^ 1, (t + 1) * 64);

    // S^T = K * Q^T : s0 = k-rows [0,32), s1 = [32,64); col q = l31
    f32x16 s0 = {}, s1 = {};
    __builtin_amdgcn_s_setprio(1);
#pragma unroll
    for (int ks = 0; ks < 4; ++ks) {
      {
        const int row = l31;
        const int ch = (ks * 2 + hi) ^ (row & 7);
        const bf16x8 kf = *reinterpret_cast<const bf16x8*>(
            reinterpret_cast<const char*>(&lK[cur][0]) + row * 128 + ch * 16);
        s0 = mfma32_bf16(kf, qf[ks], s0);
      }
      {
        const int row = 32 + l31;
        const int ch = (ks * 2 + hi) ^ (row & 7);
        const bf16x8 kf = *reinterpret_cast<const bf16x8*>(
            reinterpret_cast<const char*>(&lK[cur][0]) + row * 128 + ch * 16);
        s1 = mfma32_bf16(kf, qf[ks], s1);
      }
    }
    __builtin_amdgcn_s_setprio(0);

    // P = 2^S in place + 4-way partial row-sums (own k-half of column q=l31)
#pragma unroll
    for (int j = 0; j < 16; j += 4) {
      s0[j]     = exp2_fast(s0[j]);     rs0 += s0[j];
      s0[j + 1] = exp2_fast(s0[j + 1]); rs1 += s0[j + 1];
      s0[j + 2] = exp2_fast(s0[j + 2]); rs2 += s0[j + 2];
      s0[j + 3] = exp2_fast(s0[j + 3]); rs3 += s0[j + 3];
    }
#pragma unroll
    for (int j = 0; j < 16; j += 4) {
      s1[j]     = exp2_fast(s1[j]);     rs0 += s1[j];
      s1[j + 1] = exp2_fast(s1[j + 1]); rs1 += s1[j + 1];
      s1[j + 2] = exp2_fast(s1[j + 2]); rs2 += s1[j + 2];
      s1[j + 3] = exp2_fast(s1[j + 3]); rs3 += s1[j + 3];
    }

    // cvt_pk + permlane32_swap -> 4 PV A-fragments (k = 0..63)
    bf16x8 pa[4];
    {
      uint32_t a0 = cvt_pk_bf16(s0[0], s0[1]),   b0 = cvt_pk_bf16(s0[4], s0[5]);
      uint32_t a1 = cvt_pk_bf16(s0[2], s0[3]),   b1 = cvt_pk_bf16(s0[6], s0[7]);
      uint32_t a2 = cvt_pk_bf16(s0[8], s0[9]),   b2 = cvt_pk_bf16(s0[12], s0[13]);
      uint32_t a3 = cvt_pk_bf16(s0[10], s0[11]), b3 = cvt_pk_bf16(s0[14], s0[15]);
      permlane32_swap(a0, b0);
      permlane32_swap(a1, b1);
      permlane32_swap(a2, b2);
      permlane32_swap(a3, b3);
      union { uint32_t u[4]; bf16x8 v; } ua, ub, uc, ud;
      ua.u[0] = a0; ua.u[1] = a1; ua.u[2] = b0; ua.u[3] = b1; pa[0] = ua.v;
      ub.u[0] = a2; ub.u[1] = a3; ub.u[2] = b2; ub.u[3] = b3; pa[1] = ub.v;
      uint32_t c0 = cvt_pk_bf16(s1[0], s1[1]),   d0 = cvt_pk_bf16(s1[4], s1[5]);
      uint32_t c1 = cvt_pk_bf16(s1[2], s1[3]),   d1 = cvt_pk_bf16(s1[6], s1[7]);
      uint32_t c2 = cvt_pk_bf16(s1[8], s1[9]),   d2 = cvt_pk_bf16(s1[12], s1[13]);
      uint32_t c3 = cvt_pk_bf16(s1[10], s1[11]), d3 = cvt_pk_bf16(s1[14], s1[15]);
      permlane32_swap(c0, d0);
      permlane32_swap(c1, d1);
      permlane32_swap(c2, d2);
      permlane32_swap(c3, d3);
      uc.u[0] = c0; uc.u[1] = c1; uc.u[2] = d0; uc.u[3] = d1; pa[2] = uc.v;
      ud.u[0] = c2; ud.u[1] = c3; ud.u[2] = d2; ud.u[3] = d3; pa[3] = ud.v;
    }

    // O += P * V  (B-operand: lane holds V^T[db*32 + l31][tt*16 + hi*8 + j])
    __builtin_amdgcn_s_setprio(1);
#pragma unroll
    for (int tt = 0; tt < 4; ++tt) {
      {
        const int row = l31;
        const int ch = (tt * 2 + hi) ^ (row & 7);
        const bf16x8 vf = *reinterpret_cast<const bf16x8*>(
            reinterpret_cast<const char*>(&lV[cur][0]) + row * 128 + ch * 16);
        o0 = mfma32_bf16(pa[tt], vf, o0);
      }
      {
        const int row = 32 + l31;
        const int ch = (tt * 2 + hi) ^ (row & 7);
        const bf16x8 vf = *reinterpret_cast<const bf16x8*>(
            reinterpret_cast<const char*>(&lV[cur][0]) + row * 128 + ch * 16);
        o1 = mfma32_bf16(pa[tt], vf, o1);
      }
    }
    __builtin_amdgcn_s_setprio(0);

    __syncthreads();
    cur ^= 1;
  }

  // combine the two k-halves of the denominator (lane l <-> l^32, same q)
  const float rs = (rs0 + rs1) + (rs2 + rs3);
  uint32_t ra = __builtin_bit_cast(uint32_t, rs), rb2 = ra;
  permlane32_swap(ra, rb2);
  const float tot = __builtin_bit_cast(float, ra) + __builtin_bit_cast(float, rb2);
  const float rinv = 1.0f / tot;

  const int b = bh >> 4, h = bh & 15;
#pragma unroll
  for (int r = 0; r < 16; ++r) {
    const int qr = (r & 3) + 8 * (r >> 2) + 4 * hi;
    const float inv = __shfl(rinv, qr, 64);   // lane qr holds denom for row qr
    const size_t grow = (size_t)(b * SEQ + q0w + qr) * CH + h * DH;
    O[grow + l31]      = to_bf16(o0[r] * inv);
    O[grow + 32 + l31] = to_bf16(o1[r] * inv);
  }
}

// ---------------- launch ----------------

extern "C" void kernel_launch(void* const* d_in, const int* in_sizes, int n_in,
                              void* d_out, int out_size, void* d_ws, size_t ws_size,
                              hipStream_t stream) {
  const float* x     = (const float*)d_in[0];
  const float* w_qkv = (const float*)d_in[1];
  const float* w_out = (const float*)d_in[2];
  const float* b_out = (const float*)d_in[3];
  float* out = (float*)d_out;

  char* ws = (char*)d_ws;
  bf16_t* xb    = (bf16_t*)(ws);                       // 16 MB  [8192][1024]
  bf16_t* wqkvT = (bf16_t*)(ws + 16777216);            // 6 MB   [3072][1024]
  bf16_t* woT   = (bf16_t*)(ws + 23068672);            // 2 MB   [1024][1024]
  bf16_t* Qb    = (bf16_t*)(ws + 25165824);            // 16 MB  [64][2048][64]
  bf16_t* Kb    = (bf16_t*)(ws + 41943040);            // 16 MB  [64][2048][64]
  bf16_t* Vb    = (bf16_t*)(ws + 58720256);            // 16 MB  [64][64][2048]
  bf16_t* Ab    = xb;                                  // alias: x no longer needed post-QKV

  prep<<<3072, 256, 0, stream>>>(x, xb, w_qkv, wqkvT, w_out, woT);

  gemm_bt<0><<<(MTOT / 256) * (3 * CH / 128), 512, 0, stream>>>(
      xb, wqkvT, 3 * CH / 128, Qb, Kb, Vb, nullptr, nullptr);

  attn_fwd<<<1024, 256, 0, stream>>>(Qb, Kb, Vb, Ab);

  gemm_bt<1><<<(MTOT / 256) * (CH / 128), 512, 0, stream>>>(
      Ab, woT, CH / 128, nullptr, nullptr, nullptr, b_out, out);
}

// Round 11
// 166.086 us; speedup vs baseline: 1.1452x; 1.1452x over previous
//
#include <hip/hip_runtime.h>
#include <hip/hip_bf16.h>
#include <stdint.h>

#define SEQ   2048
#define NBH   64      // B*H
#define DH    64
#define CH    1024
#define MTOT  8192    // B*SEQ
// 1/sqrt(64) * log2(e): QK^T is computed in log2 domain, softmax uses v_exp_f32 (2^x)
#define QSCALE 0.1803368801111204f

typedef __bf16 bf16_t;
typedef bf16_t bf16x8 __attribute__((ext_vector_type(8)));
typedef float  f32x4  __attribute__((ext_vector_type(4)));
typedef float  f32x16 __attribute__((ext_vector_type(16)));

__device__ __forceinline__ bf16_t to_bf16(float f) {
  uint32_t u = __builtin_bit_cast(uint32_t, f);
  uint16_t r = (uint16_t)((u + 0x7fffu + ((u >> 16) & 1u)) >> 16);
  return __builtin_bit_cast(bf16_t, r);
}

__device__ __forceinline__ void gload_lds16(const void* g, void* l) {
  __builtin_amdgcn_global_load_lds(
      (const __attribute__((address_space(1))) uint32_t*)g,
      (__attribute__((address_space(3))) uint32_t*)l, 16, 0, 0);
}

__device__ __forceinline__ f32x4 mfma_bf16(bf16x8 a, bf16x8 b, f32x4 c) {
  return __builtin_amdgcn_mfma_f32_16x16x32_bf16(a, b, c, 0, 0, 0);
}
__device__ __forceinline__ f32x16 mfma32_bf16(bf16x8 a, bf16x8 b, f32x16 c) {
  return __builtin_amdgcn_mfma_f32_32x32x16_bf16(a, b, c, 0, 0, 0);
}

__device__ __forceinline__ float exp2_fast(float x) {
#if __has_builtin(__builtin_amdgcn_exp2f)
  return __builtin_amdgcn_exp2f(x);
#else
  float r;
  asm("v_exp_f32 %0, %1\ns_nop 0" : "=v"(r) : "v"(x));
  return r;
#endif
}

// dst.lo16 = bf16(lo), dst.hi16 = bf16(hi), RNE
__device__ __forceinline__ uint32_t cvt_pk_bf16(float lo, float hi) {
  uint32_t r;
  asm("v_cvt_pk_bf16_f32 %0, %1, %2" : "=v"(r) : "v"(lo), "v"(hi));
  return r;
}

// After: a = {a.lanes0-31, b.lanes0-31}, b = {a.lanes32-63, b.lanes32-63}
__device__ __forceinline__ void permlane32_swap(uint32_t& a, uint32_t& b) {
  asm("s_nop 1\n\tv_permlane32_swap_b32 %0, %1\n\ts_nop 1" : "+v"(a), "+v"(b));
}

// ---------------- merged prep: x->bf16 cvt + both weight transposes ----------
// blocks [0,2048): cvt x (grid-stride, 16B stores); [2048,2816): w_qkv^T;
// [2816,3072): w_out^T
__global__ __launch_bounds__(256) void prep(
    const float* __restrict__ x, bf16_t* __restrict__ xb,
    const float* __restrict__ w_qkv, bf16_t* __restrict__ wqkvT,
    const float* __restrict__ w_out, bf16_t* __restrict__ woT) {
  __shared__ float t[64 * 65];
  const int tid = threadIdx.x;
  const int blk = blockIdx.x;
  if (blk < 2048) {
    int i = (blk * 256 + tid) * 8;
    const int stride = 2048 * 256 * 8;
    for (; i < MTOT * CH; i += stride) {
      const float4 f0 = *reinterpret_cast<const float4*>(x + i);
      const float4 f1 = *reinterpret_cast<const float4*>(x + i + 4);
      const uint4 pk = make_uint4(cvt_pk_bf16(f0.x, f0.y), cvt_pk_bf16(f0.z, f0.w),
                                  cvt_pk_bf16(f1.x, f1.y), cvt_pk_bf16(f1.z, f1.w));
      *reinterpret_cast<uint4*>(xb + i) = pk;
    }
    return;
  }
  const float* W; bf16_t* WT; int Nd, nx, bi;
  if (blk < 2048 + 768) { bi = blk - 2048; W = w_qkv; WT = wqkvT; Nd = 3 * CH; nx = 48; }
  else                  { bi = blk - 2816; W = w_out; WT = woT;   Nd = CH;     nx = 16; }
  const int n0 = (bi % nx) * 64, k0 = (bi / nx) * 64;
#pragma unroll
  for (int rr = 0; rr < 16; ++rr) {
    const int idx = rr * 256 + tid;
    const int r = idx >> 6, c = idx & 63;
    t[r * 65 + c] = W[(size_t)(k0 + r) * Nd + n0 + c];
  }
  __syncthreads();
#pragma unroll
  for (int rr = 0; rr < 16; ++rr) {
    const int idx = rr * 256 + tid;
    const int nr = idx >> 6, kc = idx & 63;
    WT[(size_t)(n0 + nr) * CH + k0 + kc] = to_bf16(t[kc * 65 + nr]);
  }
}

// ---------------- GEMM (A [M][K] x BT [N][K], both bf16) ----------------
// Proven m97-style 128x128 structure, 3 blocks/CU implicit overlap.
// EPI 0: scatter into Q (scaled to log2 domain), K, V^T buffers.  EPI 1: +bias, fp32 out.
// 1D grid, XCD-swizzled (nwg % 8 == 0), nx = N/128 column tiles.

template <int EPI>
__global__ __launch_bounds__(256, 3) void gemm_bt(
    const bf16_t* __restrict__ A, const bf16_t* __restrict__ BT, int K, int nx,
    bf16_t* __restrict__ qb, bf16_t* __restrict__ kb, bf16_t* __restrict__ vb,
    const float* __restrict__ bias, float* __restrict__ out) {
  __shared__ __attribute__((aligned(16))) bf16_t lA[128 * 64];
  __shared__ __attribute__((aligned(16))) bf16_t lB[128 * 64];
  const int tid = threadIdx.x;
  const int lane = tid & 63;
  const int wv = tid >> 6;
  const int wm = wv >> 1, wn = wv & 1;

  // XCD-aware bijective swizzle: each XCD gets a contiguous chunk of tiles
  const int nwg = gridDim.x;
  int bid = blockIdx.x;
  bid = (bid & 7) * (nwg >> 3) + (bid >> 3);
  const int m0 = (bid / nx) * 128, n0 = (bid % nx) * 128;

  const int l15 = lane & 15, l16 = lane >> 4;

  f32x4 acc[4][4] = {};

  const int srow = tid >> 3;      // 0..31
  const int sch = tid & 7;        // 16B chunk within 128B row

  for (int kt = 0; kt < K; kt += 64) {
#pragma unroll
    for (int c = 0; c < 4; ++c) {
      const int row = c * 32 + srow;
      const int cs = sch ^ (row & 7);            // pre-swizzled source chunk
      gload_lds16(A + (size_t)(m0 + row) * K + kt + cs * 8, &lA[c * 2048 + tid * 8]);
    }
#pragma unroll
    for (int c = 0; c < 4; ++c) {
      const int row = c * 32 + srow;
      const int cs = sch ^ (row & 7);
      gload_lds16(BT + (size_t)(n0 + row) * K + kt + cs * 8, &lB[c * 2048 + tid * 8]);
    }
    __syncthreads();
#pragma unroll
    for (int ks = 0; ks < 2; ++ks) {
      bf16x8 af[4], bfr[4];
#pragma unroll
      for (int i = 0; i < 4; ++i) {
        const int ar = wm * 64 + i * 16 + l15;
        const int cha = (ks * 4 + l16) ^ (ar & 7);
        af[i] = *reinterpret_cast<const bf16x8*>(&lA[ar * 64 + cha * 8]);
        const int br = wn * 64 + i * 16 + l15;
        const int chb = (ks * 4 + l16) ^ (br & 7);
        bfr[i] = *reinterpret_cast<const bf16x8*>(&lB[br * 64 + chb * 8]);
      }
#pragma unroll
      for (int i = 0; i < 4; ++i)
#pragma unroll
        for (int j = 0; j < 4; ++j)
          acc[i][j] = mfma_bf16(af[i], bfr[j], acc[i][j]);
    }
    __syncthreads();
  }

  if (EPI == 0) {
    const int f0 = n0 + wn * 64;
    const int three = f0 >> 10;   // block-uniform
    if (three < 2) {
#pragma unroll
      for (int i = 0; i < 4; ++i) {
#pragma unroll
        for (int j = 0; j < 4; ++j) {
#pragma unroll
          for (int r = 0; r < 4; ++r) {
            const int m = m0 + wm * 64 + i * 16 + l16 * 4 + r;
            const int f = f0 + j * 16 + l15;
            const int h = (f >> 6) & 15, d = f & 63;
            const int bh = (m >> 11) * 16 + h;
            const int n = m & 2047;
            const float val = acc[i][j][r];
            if (three == 0)
              qb[((size_t)bh * SEQ + n) * DH + d] = to_bf16(val * QSCALE);
            else
              kb[((size_t)bh * SEQ + n) * DH + d] = to_bf16(val);
          }
        }
      }
    } else {
      // V^T: 4 consecutive n (r=0..3) at fixed d -> one packed 8B store
#pragma unroll
      for (int i = 0; i < 4; ++i) {
#pragma unroll
        for (int j = 0; j < 4; ++j) {
          const int m = m0 + wm * 64 + i * 16 + l16 * 4;   // r=0
          const int f = f0 + j * 16 + l15;
          const int h = (f >> 6) & 15, d = f & 63;
          const int bh = (m >> 11) * 16 + h;
          const int n = m & 2047;
          const uint2 pk = make_uint2(cvt_pk_bf16(acc[i][j][0], acc[i][j][1]),
                                      cvt_pk_bf16(acc[i][j][2], acc[i][j][3]));
          *reinterpret_cast<uint2*>(&vb[((size_t)bh * DH + d) * SEQ + n]) = pk;
        }
      }
    }
  } else {
#pragma unroll
    for (int j = 0; j < 4; ++j) {
      const int cc = n0 + wn * 64 + j * 16 + l15;
      const float bb = bias[cc];
#pragma unroll
      for (int i = 0; i < 4; ++i) {
#pragma unroll
        for (int r = 0; r < 4; ++r) {
          const int m = m0 + wm * 64 + i * 16 + l16 * 4 + r;
          out[(size_t)m * CH + cc] = acc[i][j][r] + bb;
        }
      }
    }
  }
}

// ---------------- flash attention (32x32 MFMA, in-register P via permlane) ----
// grid = 1024 (XCD-swizzled), block = 256 (4 waves x 32 q-rows)
// Proven-best structure (81 us): 2-buffer K/V, __syncthreads per tile.
// rs kept as 4 partial accumulators to break the 32-deep serial VALU chain.
__global__ __launch_bounds__(256, 4) void attn_fwd(
    const bf16_t* __restrict__ Q, const bf16_t* __restrict__ K,
    const bf16_t* __restrict__ V, bf16_t* __restrict__ O) {
  __shared__ __attribute__((aligned(16))) bf16_t lK[2][64 * 64];
  __shared__ __attribute__((aligned(16))) bf16_t lV[2][64 * 64];   // V^T tile [d][kt]
  const int tid = threadIdx.x;
  const int lane = tid & 63;
  const int wv = tid >> 6;
  const int l31 = lane & 31, hi = lane >> 5;

  // XCD swizzle: each XCD owns 8 consecutive bh (K/V footprint 4MB = one L2)
  const int lin = blockIdx.x;
  const int bh = (lin & 7) * 8 + ((lin >> 3) & 7);
  const int qb = lin >> 6;
  const int q0w = qb * 128 + wv * 32;

  const bf16_t* Qb = Q + (size_t)bh * SEQ * DH;
  const bf16_t* Kb = K + (size_t)bh * SEQ * DH;
  const bf16_t* Vb = V + (size_t)bh * DH * SEQ;

  // Q fragments (B-operand of 32x32x16): lane holds Q[q0w + l31][ks*16 + hi*8 + j]
  bf16x8 qf[4];
#pragma unroll
  for (int ks = 0; ks < 4; ++ks)
    qf[ks] = *reinterpret_cast<const bf16x8*>(
        Qb + (size_t)(q0w + l31) * DH + ks * 16 + hi * 8);

  f32x16 o0 = {}, o1 = {};   // O[q=crow(r,hi)][d = db*32 + l31]
  float rs0 = 0.f, rs1 = 0.f, rs2 = 0.f, rs3 = 0.f;  // partial denoms (q = l31)

  const int srow = tid >> 3;
  const int sch = tid & 7;

  auto stage = [&](int buf, int kt0) {
#pragma unroll
    for (int c = 0; c < 2; ++c) {
      const int row = c * 32 + srow;
      const int cs = sch ^ (row & 7);
      gload_lds16(Kb + (size_t)(kt0 + row) * DH + cs * 8,
                  reinterpret_cast<char*>(&lK[buf][0]) + c * 4096 + tid * 16);
      gload_lds16(Vb + (size_t)row * SEQ + kt0 + cs * 8,
                  reinterpret_cast<char*>(&lV[buf][0]) + c * 4096 + tid * 16);
    }
  };

  stage(0, 0);
  __syncthreads();
  int cur = 0;

  for (int t = 0; t < SEQ / 64; ++t) {
    if (t + 1 < SEQ / 64) stage(cur ^ 1, (t + 1) * 64);

    // S^T = K * Q^T : s0 = k-rows [0,32), s1 = [32,64); col q = l31
    f32x16 s0 = {}, s1 = {};
    __builtin_amdgcn_s_setprio(1);
#pragma unroll
    for (int ks = 0; ks < 4; ++ks) {
      {
        const int row = l31;
        const int ch = (ks * 2 + hi) ^ (row & 7);
        const bf16x8 kf = *reinterpret_cast<const bf16x8*>(
            reinterpret_cast<const char*>(&lK[cur][0]) + row * 128 + ch * 16);
        s0 = mfma32_bf16(kf, qf[ks], s0);
      }
      {
        const int row = 32 + l31;
        const int ch = (ks * 2 + hi) ^ (row & 7);
        const bf16x8 kf = *reinterpret_cast<const bf16x8*>(
            reinterpret_cast<const char*>(&lK[cur][0]) + row * 128 + ch * 16);
        s1 = mfma32_bf16(kf, qf[ks], s1);
      }
    }
    __builtin_amdgcn_s_setprio(0);

    // P = 2^S in place + 4-way partial row-sums (own k-half of column q=l31)
#pragma unroll
    for (int j = 0; j < 16; j += 4) {
      s0[j]     = exp2_fast(s0[j]);     rs0 += s0[j];
      s0[j + 1] = exp2_fast(s0[j + 1]); rs1 += s0[j + 1];
      s0[j + 2] = exp2_fast(s0[j + 2]); rs2 += s0[j + 2];
      s0[j + 3] = exp2_fast(s0[j + 3]); rs3 += s0[j + 3];
    }
#pragma unroll
    for (int j = 0; j < 16; j += 4) {
      s1[j]     = exp2_fast(s1[j]);     rs0 += s1[j];
      s1[j + 1] = exp2_fast(s1[j + 1]); rs1 += s1[j + 1];
      s1[j + 2] = exp2_fast(s1[j + 2]); rs2 += s1[j + 2];
      s1[j + 3] = exp2_fast(s1[j + 3]); rs3 += s1[j + 3];
    }

    // cvt_pk + permlane32_swap -> 4 PV A-fragments (k = 0..63)
    bf16x8 pa[4];
    {
      uint32_t a0 = cvt_pk_bf16(s0[0], s0[1]),   b0 = cvt_pk_bf16(s0[4], s0[5]);
      uint32_t a1 = cvt_pk_bf16(s0[2], s0[3]),   b1 = cvt_pk_bf16(s0[6], s0[7]);
      uint32_t a2 = cvt_pk_bf16(s0[8], s0[9]),   b2 = cvt_pk_bf16(s0[12], s0[13]);
      uint32_t a3 = cvt_pk_bf16(s0[10], s0[11]), b3 = cvt_pk_bf16(s0[14], s0[15]);
      permlane32_swap(a0, b0);
      permlane32_swap(a1, b1);
      permlane32_swap(a2, b2);
      permlane32_swap(a3, b3);
      union { uint32_t u[4]; bf16x8 v; } ua, ub, uc, ud;
      ua.u[0] = a0; ua.u[1] = a1; ua.u[2] = b0; ua.u[3] = b1; pa[0] = ua.v;
      ub.u[0] = a2; ub.u[1] = a3; ub.u[2] = b2; ub.u[3] = b3; pa[1] = ub.v;
      uint32_t c0 = cvt_pk_bf16(s1[0], s1[1]),   d0 = cvt_pk_bf16(s1[4], s1[5]);
      uint32_t c1 = cvt_pk_bf16(s1[2], s1[3]),   d1 = cvt_pk_bf16(s1[6], s1[7]);
      uint32_t c2 = cvt_pk_bf16(s1[8], s1[9]),   d2 = cvt_pk_bf16(s1[12], s1[13]);
      uint32_t c3 = cvt_pk_bf16(s1[10], s1[11]), d3 = cvt_pk_bf16(s1[14], s1[15]);
      permlane32_swap(c0, d0);
      permlane32_swap(c1, d1);
      permlane32_swap(c2, d2);
      permlane32_swap(c3, d3);
      uc.u[0] = c0; uc.u[1] = c1; uc.u[2] = d0; uc.u[3] = d1; pa[2] = uc.v;
      ud.u[0] = c2; ud.u[1] = c3; ud.u[2] = d2; ud.u[3] = d3; pa[3] = ud.v;
    }

    // O += P * V  (B-operand: lane holds V^T[db*32 + l31][tt*16 + hi*8 + j])
    __builtin_amdgcn_s_setprio(1);
#pragma unroll
    for (int tt = 0; tt < 4; ++tt) {
      {
        const int row = l31;
        const int ch = (tt * 2 + hi) ^ (row & 7);
        const bf16x8 vf = *reinterpret_cast<const bf16x8*>(
            reinterpret_cast<const char*>(&lV[cur][0]) + row * 128 + ch * 16);
        o0 = mfma32_bf16(pa[tt], vf, o0);
      }
      {
        const int row = 32 + l31;
        const int ch = (tt * 2 + hi) ^ (row & 7);
        const bf16x8 vf = *reinterpret_cast<const bf16x8*>(
            reinterpret_cast<const char*>(&lV[cur][0]) + row * 128 + ch * 16);
        o1 = mfma32_bf16(pa[tt], vf, o1);
      }
    }
    __builtin_amdgcn_s_setprio(0);

    __syncthreads();
    cur ^= 1;
  }

  // combine the two k-halves of the denominator (lane l <-> l^32, same q)
  const float rs = (rs0 + rs1) + (rs2 + rs3);
  uint32_t ra = __builtin_bit_cast(uint32_t, rs), rb2 = ra;
  permlane32_swap(ra, rb2);
  const float tot = __builtin_bit_cast(float, ra) + __builtin_bit_cast(float, rb2);
  const float rinv = 1.0f / tot;

  const int b = bh >> 4, h = bh & 15;
#pragma unroll
  for (int r = 0; r < 16; ++r) {
    const int qr = (r & 3) + 8 * (r >> 2) + 4 * hi;
    const float inv = __shfl(rinv, qr, 64);   // lane qr holds denom for row qr
    const size_t grow = (size_t)(b * SEQ + q0w + qr) * CH + h * DH;
    O[grow + l31]      = to_bf16(o0[r] * inv);
    O[grow + 32 + l31] = to_bf16(o1[r] * inv);
  }
}

// ---------------- launch ----------------

extern "C" void kernel_launch(void* const* d_in, const int* in_sizes, int n_in,
                              void* d_out, int out_size, void* d_ws, size_t ws_size,
                              hipStream_t stream) {
  const float* x     = (const float*)d_in[0];
  const float* w_qkv = (const float*)d_in[1];
  const float* w_out = (const float*)d_in[2];
  const float* b_out = (const float*)d_in[3];
  float* out = (float*)d_out;

  char* ws = (char*)d_ws;
  bf16_t* xb    = (bf16_t*)(ws);                       // 16 MB  [8192][1024]
  bf16_t* wqkvT = (bf16_t*)(ws + 16777216);            // 6 MB   [3072][1024]
  bf16_t* woT   = (bf16_t*)(ws + 23068672);            // 2 MB   [1024][1024]
  bf16_t* Qb    = (bf16_t*)(ws + 25165824);            // 16 MB  [64][2048][64]
  bf16_t* Kb    = (bf16_t*)(ws + 41943040);            // 16 MB  [64][2048][64]
  bf16_t* Vb    = (bf16_t*)(ws + 58720256);            // 16 MB  [64][64][2048]
  bf16_t* Ab    = xb;                                  // alias: x no longer needed post-QKV

  prep<<<3072, 256, 0, stream>>>(x, xb, w_qkv, wqkvT, w_out, woT);

  gemm_bt<0><<<(3 * CH / 128) * (MTOT / 128), 256, 0, stream>>>(
      xb, wqkvT, CH, 3 * CH / 128, Qb, Kb, Vb, nullptr, nullptr);

  attn_fwd<<<1024, 256, 0, stream>>>(Qb, Kb, Vb, Ab);

  gemm_bt<1><<<(CH / 128) * (MTOT / 128), 256, 0, stream>>>(
      Ab, woT, CH, CH / 128, nullptr, nullptr, nullptr, b_out, out);
}